// Round 7
// baseline (939.666 us; speedup 1.0000x reference)
//
#include <hip/hip_runtime.h>
#include <hip/hip_bf16.h>

// Problem constants (fixed by setup_inputs)
#define BB_  64
#define TT_  512
#define FF_  1024
#define HH_  31
#define GG_  124   // 4*H
#define FUT_ 16
#define TTOT_ 528  // T + future
#define OUT_ROW_ ((size_t)TTOT_ * FF_)   // per-batch stride in output

// ---- workspace layout (float indices) ----
#define PRE1_OFF ((size_t)0)                              // [512][64][128]
#define H2A_OFF  (PRE1_OFF + (size_t)TT_*64*128)          // [528*64][32]
#define WT_OFF   (H2A_OFF  + (size_t)TTOT_*64*32)         // [31][1024]
#define MV_OFF   (WT_OFF   + 31*1024)                     // [124][32]

__device__ __forceinline__ float rdlane(float v, int k) {
    return __uint_as_float(__builtin_amdgcn_readlane(__float_as_uint(v), k));
}

// repeat macros
#define REP31(M) M(0) M(1) M(2) M(3) M(4) M(5) M(6) M(7) M(8) M(9) \
                 M(10) M(11) M(12) M(13) M(14) M(15) M(16) M(17) M(18) M(19) \
                 M(20) M(21) M(22) M(23) M(24) M(25) M(26) M(27) M(28) M(29) M(30)
#define REP16E(M) M(0) M(2) M(4) M(6) M(8) M(10) M(12) M(14) \
                  M(16) M(18) M(20) M(22) M(24) M(26) M(28) M(30)
#define REP15O(M) M(1) M(3) M(5) M(7) M(9) M(11) M(13) M(15) \
                  M(17) M(19) M(21) M(23) M(25) M(27) M(29)

// ---------------- K0: transpose W_lin [1024][31] -> WT [31][1024] ----------------
__global__ void k0_prep(const float* __restrict__ Wlin, float* __restrict__ WT) {
    int i = blockIdx.x * 256 + threadIdx.x;   // 124*256 = 31744 = 1024*31 exactly
    int j = i / 31;
    int k = i - j * 31;
    WT[k * 1024 + j] = Wlin[i];
}

// ---------------- K0b: Mv[g][k] = sum_j Wih1[g][j]*Wlin[j][k]  (k=31 -> blin) ----------------
__global__ __launch_bounds__(64) void k0b_mv(
    const float* __restrict__ Wih1, const float* __restrict__ Wlin,
    const float* __restrict__ blin, float* __restrict__ Mv)
{
    int i = blockIdx.x * 64 + threadIdx.x;   // 62*64 = 3968 = 124*32
    int g = i >> 5, k = i & 31;
    const float* wr = Wih1 + (size_t)g * FF_;
    float acc = 0.0f;
    if (k < 31) {
#pragma unroll 8
        for (int j = 0; j < FF_; j++) acc += wr[j] * Wlin[j * 31 + k];
    } else {
#pragma unroll 8
        for (int j = 0; j < FF_; j++) acc += wr[j] * blin[j];
    }
    Mv[i] = acc;
}

// ---------------- K1: pregate GEMM: pre1[t][b][g] = x[b][t] . Wih1[g] + b1 ----------------
__global__ __launch_bounds__(256) void k1_pregate(
    const float* __restrict__ X,      // [B][T][F] fp32
    const float* __restrict__ Wih1,   // [G][F] fp32
    const float* __restrict__ bih1,
    const float* __restrict__ bhh1,
    float* __restrict__ pre1)         // [T][B][128]
{
    __shared__ __align__(16) float xs[32][64];    // [k][row]
    __shared__ __align__(16) float ws[32][128];   // [k][col]
    const int tid  = threadIdx.x;
    const int t    = blockIdx.x;
    const int tcol = tid & 31, trow = tid >> 5;
    const int c0 = tcol * 4, r0 = trow * 8;

    float4 acc[8];
#pragma unroll
    for (int r = 0; r < 8; r++) acc[r] = make_float4(0.f, 0.f, 0.f, 0.f);

    for (int kc = 0; kc < 32; ++kc) {
        const int k0 = kc * 32;
#pragma unroll
        for (int p = 0; p < 2; p++) {
            int i = tid + p * 256;
            int r = i >> 3, f = i & 7;
            float4 v = *(const float4*)(X + (size_t)r * TT_ * FF_ + (size_t)t * FF_ + k0 + f * 4);
            xs[f * 4 + 0][r] = v.x; xs[f * 4 + 1][r] = v.y;
            xs[f * 4 + 2][r] = v.z; xs[f * 4 + 3][r] = v.w;
        }
#pragma unroll
        for (int p = 0; p < 4; p++) {
            int i = tid + p * 256;
            int g = i >> 3, f = i & 7;
            float4 v = make_float4(0.f, 0.f, 0.f, 0.f);
            if (g < GG_) v = *(const float4*)(Wih1 + (size_t)g * FF_ + k0 + f * 4);
            ws[f * 4 + 0][g] = v.x; ws[f * 4 + 1][g] = v.y;
            ws[f * 4 + 2][g] = v.z; ws[f * 4 + 3][g] = v.w;
        }
        __syncthreads();
#pragma unroll
        for (int k = 0; k < 32; k++) {
            float4 wv = *(const float4*)&ws[k][c0];
            float4 xa = *(const float4*)&xs[k][r0];
            float4 xb = *(const float4*)&xs[k][r0 + 4];
            float rx[8] = {xa.x, xa.y, xa.z, xa.w, xb.x, xb.y, xb.z, xb.w};
#pragma unroll
            for (int r = 0; r < 8; r++) {
                acc[r].x += rx[r] * wv.x; acc[r].y += rx[r] * wv.y;
                acc[r].z += rx[r] * wv.z; acc[r].w += rx[r] * wv.w;
            }
        }
        __syncthreads();
    }
    float bias[4];
#pragma unroll
    for (int cc = 0; cc < 4; cc++) {
        int c = c0 + cc;
        bias[cc] = (c < GG_) ? (bih1[c] + bhh1[c]) : 0.0f;
    }
#pragma unroll
    for (int r = 0; r < 8; r++) {
        int m = t * 64 + r0 + r;
        float4 o = acc[r];
        o.x += bias[0]; o.y += bias[1]; o.z += bias[2]; o.w += bias[3];
        *(float4*)(pre1 + (size_t)m * 128 + c0) = o;
    }
}

// ---------------- K2: sequential recurrence, 4 BATCHES PER BLOCK (TLP) ----------------
// R6 analysis: per-step wall 1636 cy = ~366 cy VALU issue + ~1270 cy stall
// (dep chains, exp/rcp, LDS round trip, barrier) with ONE wave per SIMD --
// nothing hides the stalls. This version packs 4 batches into one 512-thread
// block (8 waves -> 2 waves/SIMD, __launch_bounds__(512,2) caps VGPR at 256
// so 2/SIMD is guaranteed; current use 76). Co-resident waves share the
// stall windows even fully in-phase: per-step wall ~ 2x issue + 1x stall
// => ~1.6x k2 throughput. Per-batch dataflow and arithmetic are textually
// identical to R6 -> bit-identical output (absmax must stay 0.001953125).
__global__ __launch_bounds__(512, 2) void k2_recur(
    const float* __restrict__ pre1,   // [T][B][128]  (bias already folded in)
    const float* __restrict__ Whh1,   // [G][H]
    const float* __restrict__ Wih2,   // [G][H]
    const float* __restrict__ Whh2,   // [G][H]
    const float* __restrict__ bih1, const float* __restrict__ bhh1,
    const float* __restrict__ bih2, const float* __restrict__ bhh2,
    const float* __restrict__ Mv,     // [124][32]  (M | v)
    float* __restrict__ h2a)          // [528*64][32]
{
    __shared__ float gA[4][2][128];   // [batch-slot][parity][gate] layer-1 gates
    __shared__ float g2[4][2][128];   // [batch-slot][parity][gate] layer-2 gates
    const int Lall = threadIdx.x;     // 0..511
    const int bsl  = Lall >> 7;       // batch slot 0..3
    const int L    = Lall & 127;      // within-batch thread 0..127
    const int bb   = blockIdx.x * 4 + bsl;
    const int j    = L & 63;          // in-wave lane
    const int gc   = (L < GG_) ? L : (GG_ - 1);   // clamped gate id
    const bool isg = (gc >= 62 && gc < 93);       // tanh gate?
    const bool selhi = (j >= 32);                 // h1-owner half of the wave
    const int sidx = selhi ? (j - 32) : j;        // state index this lane owns

    // recurrent weights as NAMED scalars: row gc of each [124][31] matrix
#define WLOAD(k) float w1_##k  = Whh1[gc * 31 + k]; \
                 float wi2_##k = Wih2[gc * 31 + k]; \
                 float wh2_##k = Whh2[gc * 31 + k];
    REP31(WLOAD)
#undef WLOAD
#define WPIN(k) asm("" : "+v"(w1_##k), "+v"(wi2_##k), "+v"(wh2_##k));
    REP31(WPIN)
#undef WPIN

    const float b2c = bih2[gc] + bhh2[gc];

    // unified state: lanes 0..30 hold (cv2,hv2)[j]; lanes 32..62 hold (cv1,hv1)[j-32]
    float hv = 0.0f, cv = 0.0f;

    // ---- prologue: layer-1 gates for t=0 (h1(-1)=0 -> dot contributes zeros) ----
    float cur0 = pre1[(size_t)bb * 128 + L];
    float pnxt = pre1[((size_t)1 * 64 + bb) * 128 + L];   // p(1)
    float pnx2 = pre1[((size_t)2 * 64 + bb) * 128 + L];   // p(2)
    {
        float pa0 = cur0, pa1 = 0.0f;
#define DPE(k) { float hk = rdlane(hv, 32 + k); pa0 += w1_##k * hk; }
#define DPO(k) { float hk = rdlane(hv, 32 + k); pa1 += w1_##k * hk; }
        REP16E(DPE)
        REP15O(DPO)
#undef DPE
#undef DPO
        float a = pa0 + pa1;
        float z = isg ? (2.0f * a) : a;
        float s = 1.0f / (1.0f + __expf(-z));
        gA[bsl][1][L] = isg ? (2.0f * s - 1.0f) : s;
    }
    __syncthreads();
    {
        // h1-owners (lanes 32..62) take h1(0); h2-owners stay at 0
        const float* gsrc = &gA[bsl][1][0];
        float ig = gsrc[sidx];
        float fg = gsrc[sidx + 31];
        float gg = gsrc[sidx + 62];
        float og = gsrc[sidx + 93];
        float cvn = fg * cv + ig * gg;
        float e = __expf(-2.0f * cvn);
        float hvn = og * (2.0f / (1.0f + e) - 1.0f);
        cv = selhi ? cvn : 0.0f;
        hv = selhi ? hvn : 0.0f;
    }

    // ---- main merged loop: iteration t computes L2(t) + L1(t+1), t = 0..510 ----
    for (int t = 0; t < TT_ - 1; t++) {
        const int pb = t & 1;
        const float cur = pnxt;          // p(t+1)
        pnxt = pnx2;
        if (t + 3 < TT_) pnx2 = pre1[((size_t)(t + 3) * 64 + bb) * 128 + L];

        // split-chain dots: h1k = rdlane(hv,32+k), h2k = rdlane(hv,k)
        float bi0 = b2c, bi1 = 0.0f, bh0 = 0.0f, bh1 = 0.0f;
        float pa0 = cur, pa1 = 0.0f;
#define DME(k) { float h1k = rdlane(hv, 32 + k); float h2k = rdlane(hv, k); \
                 bi0 += wi2_##k * h1k; bh0 += wh2_##k * h2k; pa0 += w1_##k * h1k; }
#define DMO(k) { float h1k = rdlane(hv, 32 + k); float h2k = rdlane(hv, k); \
                 bi1 += wi2_##k * h1k; bh1 += wh2_##k * h2k; pa1 += w1_##k * h1k; }
        REP16E(DME)
        REP15O(DMO)
#undef DME
#undef DMO
        float b = (bi0 + bi1) + (bh0 + bh1);
        float a = pa0 + pa1;
        {
            float z = isg ? (2.0f * b) : b;
            float s = 1.0f / (1.0f + __expf(-z));
            g2[bsl][pb][L] = isg ? (2.0f * s - 1.0f) : s;
        }
        {
            float z = isg ? (2.0f * a) : a;
            float s = 1.0f / (1.0f + __expf(-z));
            gA[bsl][pb][L] = isg ? (2.0f * s - 1.0f) : s;
        }
        __syncthreads();
        {
            // unified branchless state update: h2-owners read g2 (L2 gates of t),
            // h1-owners read gA (L1 gates of t+1). Lanes 31/63 compute harmless
            // garbage (reads stay in-bounds, nothing reads their hv).
            const float* gsrc = selhi ? &gA[bsl][pb][0] : &g2[bsl][pb][0];
            float ig = gsrc[sidx];
            float fg = gsrc[sidx + 31];
            float gg = gsrc[sidx + 62];
            float og = gsrc[sidx + 93];
            cv = fg * cv + ig * gg;
            float e = __expf(-2.0f * cv);
            hv = og * (2.0f / (1.0f + e) - 1.0f);
        }
        if (L < HH_) h2a[((size_t)t * 64 + bb) * 32 + L] = hv;   // h2(t)
    }

    // ---- tail: L2(511) only ----
    {
        float bi0 = b2c, bi1 = 0.0f, bh0 = 0.0f, bh1 = 0.0f;
#define DTE(k) { float h1k = rdlane(hv, 32 + k); float h2k = rdlane(hv, k); \
                 bi0 += wi2_##k * h1k; bh0 += wh2_##k * h2k; }
#define DTO(k) { float h1k = rdlane(hv, 32 + k); float h2k = rdlane(hv, k); \
                 bi1 += wi2_##k * h1k; bh1 += wh2_##k * h2k; }
        REP16E(DTE)
        REP15O(DTO)
#undef DTE
#undef DTO
        float b = (bi0 + bi1) + (bh0 + bh1);
        float z = isg ? (2.0f * b) : b;
        float s = 1.0f / (1.0f + __expf(-z));
        g2[bsl][1][L] = isg ? (2.0f * s - 1.0f) : s;
    }
    __syncthreads();
    {
        const float* gsrc = &g2[bsl][1][0];
        float ig = gsrc[sidx];
        float fg = gsrc[sidx + 31];
        float gg = gsrc[sidx + 62];
        float og = gsrc[sidx + 93];
        float cvn = fg * cv + ig * gg;
        float e = __expf(-2.0f * cvn);
        float hvn = og * (2.0f / (1.0f + e) - 1.0f);
        cv = selhi ? cv : cvn;          // only h2-owners update
        hv = selhi ? hv : hvn;
    }
    if (L < HH_) h2a[((size_t)(TT_ - 1) * 64 + bb) * 32 + L] = hv;   // h2(511)

    // ---- autoregressive future: pregate = M*h2 + v + b1 (1024-dot eliminated) ----
#define MLOAD(k) float m_##k = Mv[gc * 32 + k];
    REP31(MLOAD)
#undef MLOAD
    float m_31 = Mv[gc * 32 + 31];
#define MPIN(k) asm("" : "+v"(m_##k));
    REP31(MPIN)
#undef MPIN
    asm("" : "+v"(m_31));
    const float b1c = bih1[gc] + bhh1[gc];

    for (int sft = 0; sft < FUT_; sft++) {
        // phase A: L1 pregate  a = b1c + v + M*h2 + Whh1*h1
        float pa0 = b1c + m_31, pa1 = 0.0f;
#define DFE(k) { float h2k = rdlane(hv, k); pa0 += m_##k * h2k; }
#define DFO(k) { float h2k = rdlane(hv, k); pa1 += m_##k * h2k; }
        REP16E(DFE)
        REP15O(DFO)
#undef DFE
#undef DFO
#define DGE(k) { float h1k = rdlane(hv, 32 + k); pa0 += w1_##k * h1k; }
#define DGO(k) { float h1k = rdlane(hv, 32 + k); pa1 += w1_##k * h1k; }
        REP16E(DGE)
        REP15O(DGO)
#undef DGE
#undef DGO
        {
            float a = pa0 + pa1;
            float z = isg ? (2.0f * a) : a;
            float s = 1.0f / (1.0f + __expf(-z));
            gA[bsl][0][L] = isg ? (2.0f * s - 1.0f) : s;
        }
        __syncthreads();
        {
            const float* gsrc = &gA[bsl][0][0];
            float ig = gsrc[sidx];
            float fg = gsrc[sidx + 31];
            float gg = gsrc[sidx + 62];
            float og = gsrc[sidx + 93];
            float cvn = fg * cv + ig * gg;
            float e = __expf(-2.0f * cvn);
            float hvn = og * (2.0f / (1.0f + e) - 1.0f);
            cv = selhi ? cvn : cv;      // only h1-owners update
            hv = selhi ? hvn : hv;
        }
        // phase B: L2 gates
        float bi0 = b2c, bi1 = 0.0f, bh0 = 0.0f, bh1 = 0.0f;
#define DHE(k) { float h1k = rdlane(hv, 32 + k); float h2k = rdlane(hv, k); \
                 bi0 += wi2_##k * h1k; bh0 += wh2_##k * h2k; }
#define DHO(k) { float h1k = rdlane(hv, 32 + k); float h2k = rdlane(hv, k); \
                 bi1 += wi2_##k * h1k; bh1 += wh2_##k * h2k; }
        REP16E(DHE)
        REP15O(DHO)
#undef DHE
#undef DHO
        {
            float b = (bi0 + bi1) + (bh0 + bh1);
            float z = isg ? (2.0f * b) : b;
            float s = 1.0f / (1.0f + __expf(-z));
            g2[bsl][0][L] = isg ? (2.0f * s - 1.0f) : s;
        }
        __syncthreads();
        {
            const float* gsrc = &g2[bsl][0][0];
            float ig = gsrc[sidx];
            float fg = gsrc[sidx + 31];
            float gg = gsrc[sidx + 62];
            float og = gsrc[sidx + 93];
            float cvn = fg * cv + ig * gg;
            float e = __expf(-2.0f * cvn);
            float hvn = og * (2.0f / (1.0f + e) - 1.0f);
            cv = selhi ? cv : cvn;      // only h2-owners update
            hv = selhi ? hv : hvn;
        }
        if (L < HH_) h2a[((size_t)(TT_ + sft) * 64 + bb) * 32 + L] = hv;
    }
}

// ---------------- K3: output linear for ALL 528 steps: out[b][t][:] = h2 . WT + b ----------------
__global__ __launch_bounds__(256) void k3_outlin(
    const float* __restrict__ h2a,   // [528*64][32]
    const float* __restrict__ WT,    // [31][1024]
    const float* __restrict__ blin,  // [1024]
    float* __restrict__ out)         // [B][528][1024] fp32
{
    __shared__ __align__(16) float hl[16][32];
    const int tid = threadIdx.x;
    const int m0  = blockIdx.x * 16;
#pragma unroll
    for (int p = 0; p < 2; p++) {
        int i = tid + p * 256;
        int r = i >> 5, k = i & 31;
        hl[r][k] = h2a[(size_t)(m0 + r) * 32 + k];
    }
    __syncthreads();
    const int c0 = tid * 4;
    float4 bl = *(const float4*)(blin + c0);
    float4 acc[16];
#pragma unroll
    for (int r = 0; r < 16; r++) acc[r] = bl;
    for (int k = 0; k < 31; k++) {
        float4 wv = *(const float4*)(WT + k * 1024 + c0);
#pragma unroll
        for (int r = 0; r < 16; r++) {
            float h = hl[r][k];
            acc[r].x += h * wv.x; acc[r].y += h * wv.y;
            acc[r].z += h * wv.z; acc[r].w += h * wv.w;
        }
    }
    const int t  = m0 >> 6;
    const int b0 = m0 & 63;
#pragma unroll
    for (int r = 0; r < 16; r++) {
        int b = b0 + r;
        *(float4*)(out + (size_t)b * OUT_ROW_ + (size_t)t * FF_ + c0) = acc[r];
    }
}

extern "C" void kernel_launch(void* const* d_in, const int* in_sizes, int n_in,
                              void* d_out, int out_size, void* d_ws, size_t ws_size,
                              hipStream_t stream) {
    (void)in_sizes; (void)n_in; (void)out_size; (void)ws_size;
    const float* X    = (const float*)d_in[0];
    const float* Wih1 = (const float*)d_in[1];
    const float* Whh1 = (const float*)d_in[2];
    const float* bih1 = (const float*)d_in[3];
    const float* bhh1 = (const float*)d_in[4];
    const float* Wih2 = (const float*)d_in[5];
    const float* Whh2 = (const float*)d_in[6];
    const float* bih2 = (const float*)d_in[7];
    const float* bhh2 = (const float*)d_in[8];
    const float* Wlin = (const float*)d_in[9];
    const float* blin = (const float*)d_in[10];
    // d_in[11] = future = 16 (constant for this problem)

    float* ws   = (float*)d_ws;
    float* pre1 = ws + PRE1_OFF;
    float* h2a  = ws + H2A_OFF;
    float* WT   = ws + WT_OFF;
    float* Mv   = ws + MV_OFF;
    float* out  = (float*)d_out;

    hipLaunchKernelGGL(k0_prep,    dim3(124),  dim3(256), 0, stream, Wlin, WT);
    hipLaunchKernelGGL(k0b_mv,     dim3(62),   dim3(64),  0, stream, Wih1, Wlin, blin, Mv);
    hipLaunchKernelGGL(k1_pregate, dim3(TT_),  dim3(256), 0, stream, X, Wih1, bih1, bhh1, pre1);
    hipLaunchKernelGGL(k2_recur,   dim3(BB_/4), dim3(512), 0, stream, pre1, Whh1, Wih2, Whh2,
                       bih1, bhh1, bih2, bhh2, Mv, h2a);
    hipLaunchKernelGGL(k3_outlin,  dim3(TTOT_*4), dim3(256), 0, stream, h2a, WT, blin, out);
}

// Round 8
// 805.779 us; speedup vs baseline: 1.1662x; 1.1662x over previous
//
#include <hip/hip_runtime.h>
#include <hip/hip_bf16.h>

// Problem constants (fixed by setup_inputs)
#define BB_  64
#define TT_  512
#define FF_  1024
#define HH_  31
#define GG_  124   // 4*H
#define FUT_ 16
#define TTOT_ 528  // T + future
#define OUT_ROW_ ((size_t)TTOT_ * FF_)   // per-batch stride in output

// ---- workspace layout (float indices) ----
#define PRE1_OFF ((size_t)0)                              // [512][64][128]
#define H2A_OFF  (PRE1_OFF + (size_t)TT_*64*128)          // [528*64][32]
#define WT_OFF   (H2A_OFF  + (size_t)TTOT_*64*32)         // [31][1024]
#define MV_OFF   (WT_OFF   + 31*1024)                     // [124][32]

__device__ __forceinline__ float rdlane(float v, int k) {
    return __uint_as_float(__builtin_amdgcn_readlane(__float_as_uint(v), k));
}

// repeat macros
#define REP31(M) M(0) M(1) M(2) M(3) M(4) M(5) M(6) M(7) M(8) M(9) \
                 M(10) M(11) M(12) M(13) M(14) M(15) M(16) M(17) M(18) M(19) \
                 M(20) M(21) M(22) M(23) M(24) M(25) M(26) M(27) M(28) M(29) M(30)
#define REP16E(M) M(0) M(2) M(4) M(6) M(8) M(10) M(12) M(14) \
                  M(16) M(18) M(20) M(22) M(24) M(26) M(28) M(30)
#define REP15O(M) M(1) M(3) M(5) M(7) M(9) M(11) M(13) M(15) \
                  M(17) M(19) M(21) M(23) M(25) M(27) M(29)

// ---------------- K0: transpose W_lin [1024][31] -> WT [31][1024] ----------------
__global__ void k0_prep(const float* __restrict__ Wlin, float* __restrict__ WT) {
    int i = blockIdx.x * 256 + threadIdx.x;   // 124*256 = 31744 = 1024*31 exactly
    int j = i / 31;
    int k = i - j * 31;
    WT[k * 1024 + j] = Wlin[i];
}

// ---------------- K0b: Mv[g][k] = sum_j Wih1[g][j]*Wlin[j][k]  (k=31 -> blin) ----------------
__global__ __launch_bounds__(64) void k0b_mv(
    const float* __restrict__ Wih1, const float* __restrict__ Wlin,
    const float* __restrict__ blin, float* __restrict__ Mv)
{
    int i = blockIdx.x * 64 + threadIdx.x;   // 62*64 = 3968 = 124*32
    int g = i >> 5, k = i & 31;
    const float* wr = Wih1 + (size_t)g * FF_;
    float acc = 0.0f;
    if (k < 31) {
#pragma unroll 8
        for (int j = 0; j < FF_; j++) acc += wr[j] * Wlin[j * 31 + k];
    } else {
#pragma unroll 8
        for (int j = 0; j < FF_; j++) acc += wr[j] * blin[j];
    }
    Mv[i] = acc;
}

// ---------------- K1: pregate GEMM, v2: 2 timesteps/block, 512 threads ----------------
// R7 analysis: k1 (old: 512 blocks x 256 thr = 1 wave/SIMD) was ~300us --
// latency-unhidden, same disease as k2. v2: 256 blocks x 512 threads
// (8 waves = 2 waves/SIMD so LDS/barrier latency is hidden by the co-resident
// wave), tile = 128 rows (2 t x 64 b) x 128 gates, K-chunk 32. ~3200 cy of
// FMA between barriers -> 8-wave barrier amortizes (unlike k2's 300cy loop).
// Per-output accumulation order (kc asc, k asc, same chain) is unchanged
// from v1 -> pre1 is bit-identical.
__global__ __launch_bounds__(512) void k1_pregate(
    const float* __restrict__ X,      // [B][T][F] fp32
    const float* __restrict__ Wih1,   // [G][F] fp32
    const float* __restrict__ bih1,
    const float* __restrict__ bhh1,
    float* __restrict__ pre1)         // [T][B][128]
{
    __shared__ __align__(16) float xs[32][128];   // [k][row]  (row = 2t x 64b)
    __shared__ __align__(16) float ws[32][128];   // [k][gate]
    const int tid  = threadIdx.x;                 // 0..511
    const int t0   = blockIdx.x * 2;
    const int tcol = tid & 31, trow = tid >> 5;   // trow 0..15
    const int c0 = tcol * 4, r0 = trow * 8;

    float4 acc[8];
#pragma unroll
    for (int r = 0; r < 8; r++) acc[r] = make_float4(0.f, 0.f, 0.f, 0.f);

    for (int kc = 0; kc < 32; ++kc) {
        const int k0 = kc * 32;
        // stage xs: 4096 floats = 2 float4/thread. row r: b = r&63, t = t0 + (r>>6)
#pragma unroll
        for (int p = 0; p < 2; p++) {
            int i = tid + p * 512;            // 0..1023
            int r = i >> 3, f = i & 7;
            int b = r & 63, tt = t0 + (r >> 6);
            float4 v = *(const float4*)(X + (size_t)b * TT_ * FF_ + (size_t)tt * FF_ + k0 + f * 4);
            xs[f * 4 + 0][r] = v.x; xs[f * 4 + 1][r] = v.y;
            xs[f * 4 + 2][r] = v.z; xs[f * 4 + 3][r] = v.w;
        }
        // stage ws: 4096 floats = 2 float4/thread
#pragma unroll
        for (int p = 0; p < 2; p++) {
            int i = tid + p * 512;
            int g = i >> 3, f = i & 7;
            float4 v = make_float4(0.f, 0.f, 0.f, 0.f);
            if (g < GG_) v = *(const float4*)(Wih1 + (size_t)g * FF_ + k0 + f * 4);
            ws[f * 4 + 0][g] = v.x; ws[f * 4 + 1][g] = v.y;
            ws[f * 4 + 2][g] = v.z; ws[f * 4 + 3][g] = v.w;
        }
        __syncthreads();
#pragma unroll
        for (int k = 0; k < 32; k++) {
            float4 wv = *(const float4*)&ws[k][c0];
            float4 xa = *(const float4*)&xs[k][r0];
            float4 xb = *(const float4*)&xs[k][r0 + 4];
            float rx[8] = {xa.x, xa.y, xa.z, xa.w, xb.x, xb.y, xb.z, xb.w};
#pragma unroll
            for (int r = 0; r < 8; r++) {
                acc[r].x += rx[r] * wv.x; acc[r].y += rx[r] * wv.y;
                acc[r].z += rx[r] * wv.z; acc[r].w += rx[r] * wv.w;
            }
        }
        __syncthreads();
    }
    float bias[4];
#pragma unroll
    for (int cc = 0; cc < 4; cc++) {
        int c = c0 + cc;
        bias[cc] = (c < GG_) ? (bih1[c] + bhh1[c]) : 0.0f;
    }
#pragma unroll
    for (int r = 0; r < 8; r++) {
        int row = r0 + r;
        int m = (t0 + (row >> 6)) * 64 + (row & 63);
        float4 o = acc[r];
        o.x += bias[0]; o.y += bias[1]; o.z += bias[2]; o.w += bias[3];
        *(float4*)(pre1 + (size_t)m * 128 + c0) = o;
    }
}

// ---------------- K2: sequential recurrence (R6 version, verified 360us) ----------------
// Merged-phase (L2(t)+L1(t+1), one barrier/step), split state ownership
// (lanes 0..30 own layer-2 state, lanes 32..62 own layer-1 state), split
// accumulator chains (dep depth 62->16), 2-step pre1 prefetch.
// R7's 4-batch/block TLP regressed (8-wave barrier couples all stall chains)
// -> reverted to the 128-thread/1-batch form. Bit-identical output.
__global__ __attribute__((amdgpu_flat_work_group_size(128, 128), amdgpu_waves_per_eu(1)))
void k2_recur(
    const float* __restrict__ pre1,   // [T][B][128]  (bias already folded in)
    const float* __restrict__ Whh1,   // [G][H]
    const float* __restrict__ Wih2,   // [G][H]
    const float* __restrict__ Whh2,   // [G][H]
    const float* __restrict__ bih1, const float* __restrict__ bhh1,
    const float* __restrict__ bih2, const float* __restrict__ bhh2,
    const float* __restrict__ Mv,     // [124][32]  (M | v)
    float* __restrict__ h2a)          // [528*64][32]
{
    __shared__ float gA[2][128];      // layer-1 activated gates (double-buffered)
    __shared__ float g2[2][128];      // layer-2 activated gates (double-buffered)
    const int L  = threadIdx.x;       // 0..127
    const int bb = blockIdx.x;
    const int j  = L & 63;            // in-wave lane
    const int gc = (L < GG_) ? L : (GG_ - 1);   // clamped gate id for safe loads
    const bool isg = (gc >= 62 && gc < 93);     // tanh gate?
    const bool selhi = (j >= 32);               // h1-owner half of the wave
    const int sidx = selhi ? (j - 32) : j;      // state index this lane owns

    // recurrent weights as NAMED scalars: row gc of each [124][31] matrix
#define WLOAD(k) float w1_##k  = Whh1[gc * 31 + k]; \
                 float wi2_##k = Wih2[gc * 31 + k]; \
                 float wh2_##k = Whh2[gc * 31 + k];
    REP31(WLOAD)
#undef WLOAD
#define WPIN(k) asm("" : "+v"(w1_##k), "+v"(wi2_##k), "+v"(wh2_##k));
    REP31(WPIN)
#undef WPIN

    const float b2c = bih2[gc] + bhh2[gc];

    // unified state: lanes 0..30 hold (cv2,hv2)[j]; lanes 32..62 hold (cv1,hv1)[j-32]
    float hv = 0.0f, cv = 0.0f;

    // ---- prologue: layer-1 gates for t=0 (h1(-1)=0 -> dot contributes zeros) ----
    float cur0 = pre1[(size_t)bb * 128 + L];
    float pnxt = pre1[((size_t)1 * 64 + bb) * 128 + L];   // p(1)
    float pnx2 = pre1[((size_t)2 * 64 + bb) * 128 + L];   // p(2)
    {
        float pa0 = cur0, pa1 = 0.0f;
#define DPE(k) { float hk = rdlane(hv, 32 + k); pa0 += w1_##k * hk; }
#define DPO(k) { float hk = rdlane(hv, 32 + k); pa1 += w1_##k * hk; }
        REP16E(DPE)
        REP15O(DPO)
#undef DPE
#undef DPO
        float a = pa0 + pa1;
        float z = isg ? (2.0f * a) : a;
        float s = 1.0f / (1.0f + __expf(-z));
        gA[1][L] = isg ? (2.0f * s - 1.0f) : s;
    }
    __syncthreads();
    {
        // h1-owners (lanes 32..62) take h1(0); h2-owners stay at 0
        const float* gsrc = &gA[1][0];
        float ig = gsrc[sidx];
        float fg = gsrc[sidx + 31];
        float gg = gsrc[sidx + 62];
        float og = gsrc[sidx + 93];
        float cvn = fg * cv + ig * gg;
        float e = __expf(-2.0f * cvn);
        float hvn = og * (2.0f / (1.0f + e) - 1.0f);
        cv = selhi ? cvn : 0.0f;
        hv = selhi ? hvn : 0.0f;
    }

    // ---- main merged loop: iteration t computes L2(t) + L1(t+1), t = 0..510 ----
    for (int t = 0; t < TT_ - 1; t++) {
        const int pb = t & 1;
        const float cur = pnxt;          // p(t+1)
        pnxt = pnx2;
        if (t + 3 < TT_) pnx2 = pre1[((size_t)(t + 3) * 64 + bb) * 128 + L];

        // split-chain dots: h1k = rdlane(hv,32+k), h2k = rdlane(hv,k)
        float bi0 = b2c, bi1 = 0.0f, bh0 = 0.0f, bh1 = 0.0f;
        float pa0 = cur, pa1 = 0.0f;
#define DME(k) { float h1k = rdlane(hv, 32 + k); float h2k = rdlane(hv, k); \
                 bi0 += wi2_##k * h1k; bh0 += wh2_##k * h2k; pa0 += w1_##k * h1k; }
#define DMO(k) { float h1k = rdlane(hv, 32 + k); float h2k = rdlane(hv, k); \
                 bi1 += wi2_##k * h1k; bh1 += wh2_##k * h2k; pa1 += w1_##k * h1k; }
        REP16E(DME)
        REP15O(DMO)
#undef DME
#undef DMO
        float b = (bi0 + bi1) + (bh0 + bh1);
        float a = pa0 + pa1;
        {
            float z = isg ? (2.0f * b) : b;
            float s = 1.0f / (1.0f + __expf(-z));
            g2[pb][L] = isg ? (2.0f * s - 1.0f) : s;
        }
        {
            float z = isg ? (2.0f * a) : a;
            float s = 1.0f / (1.0f + __expf(-z));
            gA[pb][L] = isg ? (2.0f * s - 1.0f) : s;
        }
        __syncthreads();
        {
            // unified branchless state update: h2-owners read g2 (L2 gates of t),
            // h1-owners read gA (L1 gates of t+1). Lanes 31/63 compute harmless
            // garbage (reads stay in-bounds, nothing reads their hv).
            const float* gsrc = selhi ? &gA[pb][0] : &g2[pb][0];
            float ig = gsrc[sidx];
            float fg = gsrc[sidx + 31];
            float gg = gsrc[sidx + 62];
            float og = gsrc[sidx + 93];
            cv = fg * cv + ig * gg;
            float e = __expf(-2.0f * cv);
            hv = og * (2.0f / (1.0f + e) - 1.0f);
        }
        if (L < HH_) h2a[((size_t)t * 64 + bb) * 32 + L] = hv;   // h2(t)
    }

    // ---- tail: L2(511) only ----
    {
        float bi0 = b2c, bi1 = 0.0f, bh0 = 0.0f, bh1 = 0.0f;
#define DTE(k) { float h1k = rdlane(hv, 32 + k); float h2k = rdlane(hv, k); \
                 bi0 += wi2_##k * h1k; bh0 += wh2_##k * h2k; }
#define DTO(k) { float h1k = rdlane(hv, 32 + k); float h2k = rdlane(hv, k); \
                 bi1 += wi2_##k * h1k; bh1 += wh2_##k * h2k; }
        REP16E(DTE)
        REP15O(DTO)
#undef DTE
#undef DTO
        float b = (bi0 + bi1) + (bh0 + bh1);
        float z = isg ? (2.0f * b) : b;
        float s = 1.0f / (1.0f + __expf(-z));
        g2[1][L] = isg ? (2.0f * s - 1.0f) : s;
    }
    __syncthreads();
    {
        const float* gsrc = &g2[1][0];
        float ig = gsrc[sidx];
        float fg = gsrc[sidx + 31];
        float gg = gsrc[sidx + 62];
        float og = gsrc[sidx + 93];
        float cvn = fg * cv + ig * gg;
        float e = __expf(-2.0f * cvn);
        float hvn = og * (2.0f / (1.0f + e) - 1.0f);
        cv = selhi ? cv : cvn;          // only h2-owners update
        hv = selhi ? hv : hvn;
    }
    if (L < HH_) h2a[((size_t)(TT_ - 1) * 64 + bb) * 32 + L] = hv;   // h2(511)

    // ---- autoregressive future: pregate = M*h2 + v + b1 (1024-dot eliminated) ----
#define MLOAD(k) float m_##k = Mv[gc * 32 + k];
    REP31(MLOAD)
#undef MLOAD
    float m_31 = Mv[gc * 32 + 31];
#define MPIN(k) asm("" : "+v"(m_##k));
    REP31(MPIN)
#undef MPIN
    asm("" : "+v"(m_31));
    const float b1c = bih1[gc] + bhh1[gc];

    for (int sft = 0; sft < FUT_; sft++) {
        // phase A: L1 pregate  a = b1c + v + M*h2 + Whh1*h1
        float pa0 = b1c + m_31, pa1 = 0.0f;
#define DFE(k) { float h2k = rdlane(hv, k); pa0 += m_##k * h2k; }
#define DFO(k) { float h2k = rdlane(hv, k); pa1 += m_##k * h2k; }
        REP16E(DFE)
        REP15O(DFO)
#undef DFE
#undef DFO
#define DGE(k) { float h1k = rdlane(hv, 32 + k); pa0 += w1_##k * h1k; }
#define DGO(k) { float h1k = rdlane(hv, 32 + k); pa1 += w1_##k * h1k; }
        REP16E(DGE)
        REP15O(DGO)
#undef DGE
#undef DGO
        {
            float a = pa0 + pa1;
            float z = isg ? (2.0f * a) : a;
            float s = 1.0f / (1.0f + __expf(-z));
            gA[0][L] = isg ? (2.0f * s - 1.0f) : s;
        }
        __syncthreads();
        {
            const float* gsrc = &gA[0][0];
            float ig = gsrc[sidx];
            float fg = gsrc[sidx + 31];
            float gg = gsrc[sidx + 62];
            float og = gsrc[sidx + 93];
            float cvn = fg * cv + ig * gg;
            float e = __expf(-2.0f * cvn);
            float hvn = og * (2.0f / (1.0f + e) - 1.0f);
            cv = selhi ? cvn : cv;      // only h1-owners update
            hv = selhi ? hvn : hv;
        }
        // phase B: L2 gates
        float bi0 = b2c, bi1 = 0.0f, bh0 = 0.0f, bh1 = 0.0f;
#define DHE(k) { float h1k = rdlane(hv, 32 + k); float h2k = rdlane(hv, k); \
                 bi0 += wi2_##k * h1k; bh0 += wh2_##k * h2k; }
#define DHO(k) { float h1k = rdlane(hv, 32 + k); float h2k = rdlane(hv, k); \
                 bi1 += wi2_##k * h1k; bh1 += wh2_##k * h2k; }
        REP16E(DHE)
        REP15O(DHO)
#undef DHE
#undef DHO
        {
            float b = (bi0 + bi1) + (bh0 + bh1);
            float z = isg ? (2.0f * b) : b;
            float s = 1.0f / (1.0f + __expf(-z));
            g2[0][L] = isg ? (2.0f * s - 1.0f) : s;
        }
        __syncthreads();
        {
            const float* gsrc = &g2[0][0];
            float ig = gsrc[sidx];
            float fg = gsrc[sidx + 31];
            float gg = gsrc[sidx + 62];
            float og = gsrc[sidx + 93];
            float cvn = fg * cv + ig * gg;
            float e = __expf(-2.0f * cvn);
            float hvn = og * (2.0f / (1.0f + e) - 1.0f);
            cv = selhi ? cv : cvn;      // only h2-owners update
            hv = selhi ? hv : hvn;
        }
        if (L < HH_) h2a[((size_t)(TT_ + sft) * 64 + bb) * 32 + L] = hv;
    }
}

// ---------------- K3: output linear for ALL 528 steps: out[b][t][:] = h2 . WT + b ----------------
__global__ __launch_bounds__(256) void k3_outlin(
    const float* __restrict__ h2a,   // [528*64][32]
    const float* __restrict__ WT,    // [31][1024]
    const float* __restrict__ blin,  // [1024]
    float* __restrict__ out)         // [B][528][1024] fp32
{
    __shared__ __align__(16) float hl[16][32];
    const int tid = threadIdx.x;
    const int m0  = blockIdx.x * 16;
#pragma unroll
    for (int p = 0; p < 2; p++) {
        int i = tid + p * 256;
        int r = i >> 5, k = i & 31;
        hl[r][k] = h2a[(size_t)(m0 + r) * 32 + k];
    }
    __syncthreads();
    const int c0 = tid * 4;
    float4 bl = *(const float4*)(blin + c0);
    float4 acc[16];
#pragma unroll
    for (int r = 0; r < 16; r++) acc[r] = bl;
    for (int k = 0; k < 31; k++) {
        float4 wv = *(const float4*)(WT + k * 1024 + c0);
#pragma unroll
        for (int r = 0; r < 16; r++) {
            float h = hl[r][k];
            acc[r].x += h * wv.x; acc[r].y += h * wv.y;
            acc[r].z += h * wv.z; acc[r].w += h * wv.w;
        }
    }
    const int t  = m0 >> 6;
    const int b0 = m0 & 63;
#pragma unroll
    for (int r = 0; r < 16; r++) {
        int b = b0 + r;
        *(float4*)(out + (size_t)b * OUT_ROW_ + (size_t)t * FF_ + c0) = acc[r];
    }
}

extern "C" void kernel_launch(void* const* d_in, const int* in_sizes, int n_in,
                              void* d_out, int out_size, void* d_ws, size_t ws_size,
                              hipStream_t stream) {
    (void)in_sizes; (void)n_in; (void)out_size; (void)ws_size;
    const float* X    = (const float*)d_in[0];
    const float* Wih1 = (const float*)d_in[1];
    const float* Whh1 = (const float*)d_in[2];
    const float* bih1 = (const float*)d_in[3];
    const float* bhh1 = (const float*)d_in[4];
    const float* Wih2 = (const float*)d_in[5];
    const float* Whh2 = (const float*)d_in[6];
    const float* bih2 = (const float*)d_in[7];
    const float* bhh2 = (const float*)d_in[8];
    const float* Wlin = (const float*)d_in[9];
    const float* blin = (const float*)d_in[10];
    // d_in[11] = future = 16 (constant for this problem)

    float* ws   = (float*)d_ws;
    float* pre1 = ws + PRE1_OFF;
    float* h2a  = ws + H2A_OFF;
    float* WT   = ws + WT_OFF;
    float* Mv   = ws + MV_OFF;
    float* out  = (float*)d_out;

    hipLaunchKernelGGL(k0_prep,    dim3(124),  dim3(256), 0, stream, Wlin, WT);
    hipLaunchKernelGGL(k0b_mv,     dim3(62),   dim3(64),  0, stream, Wih1, Wlin, blin, Mv);
    hipLaunchKernelGGL(k1_pregate, dim3(TT_/2), dim3(512), 0, stream, X, Wih1, bih1, bhh1, pre1);
    hipLaunchKernelGGL(k2_recur,   dim3(BB_),  dim3(128), 0, stream, pre1, Whh1, Wih2, Whh2,
                       bih1, bhh1, bih2, bhh2, Mv, h2a);
    hipLaunchKernelGGL(k3_outlin,  dim3(TTOT_*4), dim3(256), 0, stream, h2a, WT, blin, out);
}

// Round 9
// 776.806 us; speedup vs baseline: 1.2097x; 1.0373x over previous
//
#include <hip/hip_runtime.h>
#include <hip/hip_bf16.h>

// Problem constants (fixed by setup_inputs)
#define BB_  64
#define TT_  512
#define FF_  1024
#define HH_  31
#define GG_  124   // 4*H
#define FUT_ 16
#define TTOT_ 528  // T + future
#define OUT_ROW_ ((size_t)TTOT_ * FF_)   // per-batch stride in output

// ---- workspace layout (float indices) ----
#define PRE1_OFF ((size_t)0)                              // [512][64][128]
#define H2A_OFF  (PRE1_OFF + (size_t)TT_*64*128)          // [528*64][32]
#define WT_OFF   (H2A_OFF  + (size_t)TTOT_*64*32)         // [31][1024]
#define MV_OFF   (WT_OFF   + 31*1024)                     // [124][32]

__device__ __forceinline__ float rdlane(float v, int k) {
    return __uint_as_float(__builtin_amdgcn_readlane(__float_as_uint(v), k));
}

// repeat macros
#define REP31(M) M(0) M(1) M(2) M(3) M(4) M(5) M(6) M(7) M(8) M(9) \
                 M(10) M(11) M(12) M(13) M(14) M(15) M(16) M(17) M(18) M(19) \
                 M(20) M(21) M(22) M(23) M(24) M(25) M(26) M(27) M(28) M(29) M(30)
#define REP16E(M) M(0) M(2) M(4) M(6) M(8) M(10) M(12) M(14) \
                  M(16) M(18) M(20) M(22) M(24) M(26) M(28) M(30)
#define REP15O(M) M(1) M(3) M(5) M(7) M(9) M(11) M(13) M(15) \
                  M(17) M(19) M(21) M(23) M(25) M(27) M(29)

// ---------------- K_FRONT: fused k1(pregate GEMM v3) + k0(WT transpose) + k0b(Mv) ----
// blocks 0..255   : k1 role -- 2 timesteps x 128 gates, 256 thr, 8x8 register tile
//                   (LDS traffic 25->16.8 MB/block vs v2's 8x4 tile; VALU/LDS balanced)
// blocks 256..379 : k0 role -- transpose W_lin [1024][31] -> WT [31][1024]
// blocks 380..395 : k0b role -- Mv[g][k] = sum_j Wih1[g][j]*Wlin[j][k] (k=31 -> blin)
// All three are mutually independent (read-only on inputs). Fusing removes 2
// launch gaps. Per-output accumulation order in the k1 role is (kc asc, k asc),
// textually identical chain to v1/v2 -> pre1 bit-identical.
__global__ __launch_bounds__(256) void k_front(
    const float* __restrict__ X,      // [B][T][F] fp32
    const float* __restrict__ Wih1,   // [G][F] fp32
    const float* __restrict__ bih1,
    const float* __restrict__ bhh1,
    const float* __restrict__ Wlin,   // [1024][31]
    const float* __restrict__ blin,   // [1024]
    float* __restrict__ pre1,         // [T][B][128]
    float* __restrict__ WT,           // [31][1024]
    float* __restrict__ Mv)           // [124][32]
{
    __shared__ __align__(16) float xs[32][128];   // [k][row]  (row = 2t x 64b)
    __shared__ __align__(16) float ws[32][128];   // [k][gate]
    const int blk = blockIdx.x;
    const int tid = threadIdx.x;

    if (blk < 256) {
        // ---------------- k1 role ----------------
        const int t0   = blk * 2;
        const int tcol = tid & 15, trow = tid >> 4;   // 16 x 16 thread grid
        const int c0 = tcol * 8, r0 = trow * 8;

        float4 a0[8], a1[8];
#pragma unroll
        for (int r = 0; r < 8; r++) { a0[r] = make_float4(0.f,0.f,0.f,0.f); a1[r] = a0[r]; }

        for (int kc = 0; kc < 32; ++kc) {
            const int k0f = kc * 32;
            // stage xs: 4096 floats = 4 float4/thread
#pragma unroll
            for (int p = 0; p < 4; p++) {
                int i = tid + p * 256;            // 0..1023
                int r = i >> 3, f = i & 7;
                int bb = r & 63, tt = t0 + (r >> 6);
                float4 v = *(const float4*)(X + (size_t)bb * TT_ * FF_ + (size_t)tt * FF_ + k0f + f * 4);
                xs[f * 4 + 0][r] = v.x; xs[f * 4 + 1][r] = v.y;
                xs[f * 4 + 2][r] = v.z; xs[f * 4 + 3][r] = v.w;
            }
            // stage ws: 4096 floats = 4 float4/thread
#pragma unroll
            for (int p = 0; p < 4; p++) {
                int i = tid + p * 256;
                int g = i >> 3, f = i & 7;
                float4 v = make_float4(0.f, 0.f, 0.f, 0.f);
                if (g < GG_) v = *(const float4*)(Wih1 + (size_t)g * FF_ + k0f + f * 4);
                ws[f * 4 + 0][g] = v.x; ws[f * 4 + 1][g] = v.y;
                ws[f * 4 + 2][g] = v.z; ws[f * 4 + 3][g] = v.w;
            }
            __syncthreads();
#pragma unroll
            for (int k = 0; k < 32; k++) {
                float4 wv0 = *(const float4*)&ws[k][c0];
                float4 wv1 = *(const float4*)&ws[k][c0 + 4];
                float4 xa  = *(const float4*)&xs[k][r0];
                float4 xb  = *(const float4*)&xs[k][r0 + 4];
                float rx[8] = {xa.x, xa.y, xa.z, xa.w, xb.x, xb.y, xb.z, xb.w};
#pragma unroll
                for (int r = 0; r < 8; r++) {
                    a0[r].x += rx[r] * wv0.x; a0[r].y += rx[r] * wv0.y;
                    a0[r].z += rx[r] * wv0.z; a0[r].w += rx[r] * wv0.w;
                    a1[r].x += rx[r] * wv1.x; a1[r].y += rx[r] * wv1.y;
                    a1[r].z += rx[r] * wv1.z; a1[r].w += rx[r] * wv1.w;
                }
            }
            __syncthreads();
        }
        float bias0[4], bias1[4];
#pragma unroll
        for (int cc = 0; cc < 4; cc++) {
            int c = c0 + cc;
            bias0[cc] = (c < GG_) ? (bih1[c] + bhh1[c]) : 0.0f;
            c = c0 + 4 + cc;
            bias1[cc] = (c < GG_) ? (bih1[c] + bhh1[c]) : 0.0f;
        }
#pragma unroll
        for (int r = 0; r < 8; r++) {
            int row = r0 + r;
            int m = (t0 + (row >> 6)) * 64 + (row & 63);
            float4 o0 = a0[r], o1 = a1[r];
            o0.x += bias0[0]; o0.y += bias0[1]; o0.z += bias0[2]; o0.w += bias0[3];
            o1.x += bias1[0]; o1.y += bias1[1]; o1.z += bias1[2]; o1.w += bias1[3];
            *(float4*)(pre1 + (size_t)m * 128 + c0)     = o0;
            *(float4*)(pre1 + (size_t)m * 128 + c0 + 4) = o1;
        }
    } else if (blk < 380) {
        // ---------------- k0 role: transpose W_lin ----------------
        int i = (blk - 256) * 256 + tid;   // 124*256 = 31744 = 1024*31 exactly
        int j = i / 31;
        int k = i - j * 31;
        WT[k * 1024 + j] = Wlin[i];
    } else {
        // ---------------- k0b role: Mv ----------------
        int idx = (blk - 380) * 256 + tid;   // 16*256 = 4096 >= 3968
        if (idx < GG_ * 32) {
            int g = idx >> 5, k = idx & 31;
            const float* wr = Wih1 + (size_t)g * FF_;
            float acc = 0.0f;
            if (k < 31) {
#pragma unroll 8
                for (int j = 0; j < FF_; j++) acc += wr[j] * Wlin[j * 31 + k];
            } else {
#pragma unroll 8
                for (int j = 0; j < FF_; j++) acc += wr[j] * blin[j];
            }
            Mv[idx] = acc;
        }
    }
}

// ---------------- K2: sequential recurrence (R6 version, verified 360us) ----------------
// Merged-phase (L2(t)+L1(t+1), one barrier/step), split state ownership
// (lanes 0..30 own layer-2 state, lanes 32..62 own layer-1 state), split
// accumulator chains (dep depth 62->16), 2-step pre1 prefetch.
// R7's 4-batch/block TLP regressed (8-wave barrier couples all stall chains)
// -> kept at the 128-thread/1-batch form. Bit-identical output.
__global__ __attribute__((amdgpu_flat_work_group_size(128, 128), amdgpu_waves_per_eu(1)))
void k2_recur(
    const float* __restrict__ pre1,   // [T][B][128]  (bias already folded in)
    const float* __restrict__ Whh1,   // [G][H]
    const float* __restrict__ Wih2,   // [G][H]
    const float* __restrict__ Whh2,   // [G][H]
    const float* __restrict__ bih1, const float* __restrict__ bhh1,
    const float* __restrict__ bih2, const float* __restrict__ bhh2,
    const float* __restrict__ Mv,     // [124][32]  (M | v)
    float* __restrict__ h2a)          // [528*64][32]
{
    __shared__ float gA[2][128];      // layer-1 activated gates (double-buffered)
    __shared__ float g2[2][128];      // layer-2 activated gates (double-buffered)
    const int L  = threadIdx.x;       // 0..127
    const int bb = blockIdx.x;
    const int j  = L & 63;            // in-wave lane
    const int gc = (L < GG_) ? L : (GG_ - 1);   // clamped gate id for safe loads
    const bool isg = (gc >= 62 && gc < 93);     // tanh gate?
    const bool selhi = (j >= 32);               // h1-owner half of the wave
    const int sidx = selhi ? (j - 32) : j;      // state index this lane owns

    // recurrent weights as NAMED scalars: row gc of each [124][31] matrix
#define WLOAD(k) float w1_##k  = Whh1[gc * 31 + k]; \
                 float wi2_##k = Wih2[gc * 31 + k]; \
                 float wh2_##k = Whh2[gc * 31 + k];
    REP31(WLOAD)
#undef WLOAD
#define WPIN(k) asm("" : "+v"(w1_##k), "+v"(wi2_##k), "+v"(wh2_##k));
    REP31(WPIN)
#undef WPIN

    const float b2c = bih2[gc] + bhh2[gc];

    // unified state: lanes 0..30 hold (cv2,hv2)[j]; lanes 32..62 hold (cv1,hv1)[j-32]
    float hv = 0.0f, cv = 0.0f;

    // ---- prologue: layer-1 gates for t=0 (h1(-1)=0 -> dot contributes zeros) ----
    float cur0 = pre1[(size_t)bb * 128 + L];
    float pnxt = pre1[((size_t)1 * 64 + bb) * 128 + L];   // p(1)
    float pnx2 = pre1[((size_t)2 * 64 + bb) * 128 + L];   // p(2)
    {
        float pa0 = cur0, pa1 = 0.0f;
#define DPE(k) { float hk = rdlane(hv, 32 + k); pa0 += w1_##k * hk; }
#define DPO(k) { float hk = rdlane(hv, 32 + k); pa1 += w1_##k * hk; }
        REP16E(DPE)
        REP15O(DPO)
#undef DPE
#undef DPO
        float a = pa0 + pa1;
        float z = isg ? (2.0f * a) : a;
        float s = 1.0f / (1.0f + __expf(-z));
        gA[1][L] = isg ? (2.0f * s - 1.0f) : s;
    }
    __syncthreads();
    {
        // h1-owners (lanes 32..62) take h1(0); h2-owners stay at 0
        const float* gsrc = &gA[1][0];
        float ig = gsrc[sidx];
        float fg = gsrc[sidx + 31];
        float gg = gsrc[sidx + 62];
        float og = gsrc[sidx + 93];
        float cvn = fg * cv + ig * gg;
        float e = __expf(-2.0f * cvn);
        float hvn = og * (2.0f / (1.0f + e) - 1.0f);
        cv = selhi ? cvn : 0.0f;
        hv = selhi ? hvn : 0.0f;
    }

    // ---- main merged loop: iteration t computes L2(t) + L1(t+1), t = 0..510 ----
    for (int t = 0; t < TT_ - 1; t++) {
        const int pb = t & 1;
        const float cur = pnxt;          // p(t+1)
        pnxt = pnx2;
        if (t + 3 < TT_) pnx2 = pre1[((size_t)(t + 3) * 64 + bb) * 128 + L];

        // split-chain dots: h1k = rdlane(hv,32+k), h2k = rdlane(hv,k)
        float bi0 = b2c, bi1 = 0.0f, bh0 = 0.0f, bh1 = 0.0f;
        float pa0 = cur, pa1 = 0.0f;
#define DME(k) { float h1k = rdlane(hv, 32 + k); float h2k = rdlane(hv, k); \
                 bi0 += wi2_##k * h1k; bh0 += wh2_##k * h2k; pa0 += w1_##k * h1k; }
#define DMO(k) { float h1k = rdlane(hv, 32 + k); float h2k = rdlane(hv, k); \
                 bi1 += wi2_##k * h1k; bh1 += wh2_##k * h2k; pa1 += w1_##k * h1k; }
        REP16E(DME)
        REP15O(DMO)
#undef DME
#undef DMO
        float b = (bi0 + bi1) + (bh0 + bh1);
        float a = pa0 + pa1;
        {
            float z = isg ? (2.0f * b) : b;
            float s = 1.0f / (1.0f + __expf(-z));
            g2[pb][L] = isg ? (2.0f * s - 1.0f) : s;
        }
        {
            float z = isg ? (2.0f * a) : a;
            float s = 1.0f / (1.0f + __expf(-z));
            gA[pb][L] = isg ? (2.0f * s - 1.0f) : s;
        }
        __syncthreads();
        {
            // unified branchless state update: h2-owners read g2 (L2 gates of t),
            // h1-owners read gA (L1 gates of t+1). Lanes 31/63 compute harmless
            // garbage (reads stay in-bounds, nothing reads their hv).
            const float* gsrc = selhi ? &gA[pb][0] : &g2[pb][0];
            float ig = gsrc[sidx];
            float fg = gsrc[sidx + 31];
            float gg = gsrc[sidx + 62];
            float og = gsrc[sidx + 93];
            cv = fg * cv + ig * gg;
            float e = __expf(-2.0f * cv);
            hv = og * (2.0f / (1.0f + e) - 1.0f);
        }
        if (L < HH_) h2a[((size_t)t * 64 + bb) * 32 + L] = hv;   // h2(t)
    }

    // ---- tail: L2(511) only ----
    {
        float bi0 = b2c, bi1 = 0.0f, bh0 = 0.0f, bh1 = 0.0f;
#define DTE(k) { float h1k = rdlane(hv, 32 + k); float h2k = rdlane(hv, k); \
                 bi0 += wi2_##k * h1k; bh0 += wh2_##k * h2k; }
#define DTO(k) { float h1k = rdlane(hv, 32 + k); float h2k = rdlane(hv, k); \
                 bi1 += wi2_##k * h1k; bh1 += wh2_##k * h2k; }
        REP16E(DTE)
        REP15O(DTO)
#undef DTE
#undef DTO
        float b = (bi0 + bi1) + (bh0 + bh1);
        float z = isg ? (2.0f * b) : b;
        float s = 1.0f / (1.0f + __expf(-z));
        g2[1][L] = isg ? (2.0f * s - 1.0f) : s;
    }
    __syncthreads();
    {
        const float* gsrc = &g2[1][0];
        float ig = gsrc[sidx];
        float fg = gsrc[sidx + 31];
        float gg = gsrc[sidx + 62];
        float og = gsrc[sidx + 93];
        float cvn = fg * cv + ig * gg;
        float e = __expf(-2.0f * cvn);
        float hvn = og * (2.0f / (1.0f + e) - 1.0f);
        cv = selhi ? cv : cvn;          // only h2-owners update
        hv = selhi ? hv : hvn;
    }
    if (L < HH_) h2a[((size_t)(TT_ - 1) * 64 + bb) * 32 + L] = hv;   // h2(511)

    // ---- autoregressive future: pregate = M*h2 + v + b1 (1024-dot eliminated) ----
#define MLOAD(k) float m_##k = Mv[gc * 32 + k];
    REP31(MLOAD)
#undef MLOAD
    float m_31 = Mv[gc * 32 + 31];
#define MPIN(k) asm("" : "+v"(m_##k));
    REP31(MPIN)
#undef MPIN
    asm("" : "+v"(m_31));
    const float b1c = bih1[gc] + bhh1[gc];

    for (int sft = 0; sft < FUT_; sft++) {
        // phase A: L1 pregate  a = b1c + v + M*h2 + Whh1*h1
        float pa0 = b1c + m_31, pa1 = 0.0f;
#define DFE(k) { float h2k = rdlane(hv, k); pa0 += m_##k * h2k; }
#define DFO(k) { float h2k = rdlane(hv, k); pa1 += m_##k * h2k; }
        REP16E(DFE)
        REP15O(DFO)
#undef DFE
#undef DFO
#define DGE(k) { float h1k = rdlane(hv, 32 + k); pa0 += w1_##k * h1k; }
#define DGO(k) { float h1k = rdlane(hv, 32 + k); pa1 += w1_##k * h1k; }
        REP16E(DGE)
        REP15O(DGO)
#undef DGE
#undef DGO
        {
            float a = pa0 + pa1;
            float z = isg ? (2.0f * a) : a;
            float s = 1.0f / (1.0f + __expf(-z));
            gA[0][L] = isg ? (2.0f * s - 1.0f) : s;
        }
        __syncthreads();
        {
            const float* gsrc = &gA[0][0];
            float ig = gsrc[sidx];
            float fg = gsrc[sidx + 31];
            float gg = gsrc[sidx + 62];
            float og = gsrc[sidx + 93];
            float cvn = fg * cv + ig * gg;
            float e = __expf(-2.0f * cvn);
            float hvn = og * (2.0f / (1.0f + e) - 1.0f);
            cv = selhi ? cvn : cv;      // only h1-owners update
            hv = selhi ? hvn : hv;
        }
        // phase B: L2 gates
        float bi0 = b2c, bi1 = 0.0f, bh0 = 0.0f, bh1 = 0.0f;
#define DHE(k) { float h1k = rdlane(hv, 32 + k); float h2k = rdlane(hv, k); \
                 bi0 += wi2_##k * h1k; bh0 += wh2_##k * h2k; }
#define DHO(k) { float h1k = rdlane(hv, 32 + k); float h2k = rdlane(hv, k); \
                 bi1 += wi2_##k * h1k; bh1 += wh2_##k * h2k; }
        REP16E(DHE)
        REP15O(DHO)
#undef DHE
#undef DHO
        {
            float b = (bi0 + bi1) + (bh0 + bh1);
            float z = isg ? (2.0f * b) : b;
            float s = 1.0f / (1.0f + __expf(-z));
            g2[0][L] = isg ? (2.0f * s - 1.0f) : s;
        }
        __syncthreads();
        {
            const float* gsrc = &g2[0][0];
            float ig = gsrc[sidx];
            float fg = gsrc[sidx + 31];
            float gg = gsrc[sidx + 62];
            float og = gsrc[sidx + 93];
            float cvn = fg * cv + ig * gg;
            float e = __expf(-2.0f * cvn);
            float hvn = og * (2.0f / (1.0f + e) - 1.0f);
            cv = selhi ? cv : cvn;      // only h2-owners update
            hv = selhi ? hv : hvn;
        }
        if (L < HH_) h2a[((size_t)(TT_ + sft) * 64 + bb) * 32 + L] = hv;
    }
}

// ---------------- K3 v2: output linear, 32 rows/block ----------------
// Halves WT re-fetch (124 KB per block, now 1056 blocks) and doubles
// per-thread ILP (32 independent accumulator chains). Per-output chain
// (bias, then k ascending) unchanged -> bit-identical output.
__global__ __launch_bounds__(256) void k3_outlin(
    const float* __restrict__ h2a,   // [528*64][32]
    const float* __restrict__ WT,    // [31][1024]
    const float* __restrict__ blin,  // [1024]
    float* __restrict__ out)         // [B][528][1024] fp32
{
    __shared__ __align__(16) float hl[32][32];
    const int tid = threadIdx.x;
    const int m0  = blockIdx.x * 32;
#pragma unroll
    for (int p = 0; p < 4; p++) {
        int i = tid + p * 256;
        int r = i >> 5, k = i & 31;
        hl[r][k] = h2a[(size_t)(m0 + r) * 32 + k];
    }
    __syncthreads();
    const int c0 = tid * 4;
    float4 bl = *(const float4*)(blin + c0);
    float4 acc[32];
#pragma unroll
    for (int r = 0; r < 32; r++) acc[r] = bl;
    for (int k = 0; k < 31; k++) {
        float4 wv = *(const float4*)(WT + k * 1024 + c0);
#pragma unroll
        for (int r = 0; r < 32; r++) {
            float h = hl[r][k];
            acc[r].x += h * wv.x; acc[r].y += h * wv.y;
            acc[r].z += h * wv.z; acc[r].w += h * wv.w;
        }
    }
    const int t  = m0 >> 6;
    const int b0 = m0 & 63;
#pragma unroll
    for (int r = 0; r < 32; r++) {
        int b = b0 + r;
        *(float4*)(out + (size_t)b * OUT_ROW_ + (size_t)t * FF_ + c0) = acc[r];
    }
}

extern "C" void kernel_launch(void* const* d_in, const int* in_sizes, int n_in,
                              void* d_out, int out_size, void* d_ws, size_t ws_size,
                              hipStream_t stream) {
    (void)in_sizes; (void)n_in; (void)out_size; (void)ws_size;
    const float* X    = (const float*)d_in[0];
    const float* Wih1 = (const float*)d_in[1];
    const float* Whh1 = (const float*)d_in[2];
    const float* bih1 = (const float*)d_in[3];
    const float* bhh1 = (const float*)d_in[4];
    const float* Wih2 = (const float*)d_in[5];
    const float* Whh2 = (const float*)d_in[6];
    const float* bih2 = (const float*)d_in[7];
    const float* bhh2 = (const float*)d_in[8];
    const float* Wlin = (const float*)d_in[9];
    const float* blin = (const float*)d_in[10];
    // d_in[11] = future = 16 (constant for this problem)

    float* ws   = (float*)d_ws;
    float* pre1 = ws + PRE1_OFF;
    float* h2a  = ws + H2A_OFF;
    float* WT   = ws + WT_OFF;
    float* Mv   = ws + MV_OFF;
    float* out  = (float*)d_out;

    hipLaunchKernelGGL(k_front,   dim3(396),    dim3(256), 0, stream,
                       X, Wih1, bih1, bhh1, Wlin, blin, pre1, WT, Mv);
    hipLaunchKernelGGL(k2_recur,  dim3(BB_),    dim3(128), 0, stream, pre1, Whh1, Wih2, Whh2,
                       bih1, bhh1, bih2, bhh2, Mv, h2a);
    hipLaunchKernelGGL(k3_outlin, dim3(TTOT_*2), dim3(256), 0, stream, h2a, WT, blin, out);
}